// Round 2
// baseline (202.036 us; speedup 1.0000x reference)
//
#include <hip/hip_runtime.h>
#include <stdint.h>

// Problem constants (fixed by reference setup_inputs):
//   qt:     (H=25920, S=64, D=64) f32
//   k:      (H, 1, D) f32          -- DEAD: softmax over singleton axis == 1
//   scaleb: (H, 1, 1) f32          -- DEAD: same reason
//   biasb:  (H, 1, 1) f32          -- zeros in setup; a5 = mask * biasb/keep
// out = qt + broadcast(a5) ; a5[h,s] = (bernoulli_keep ? 1/keep : 0) * biasb[h]
//
// Memory-bound: ~850 MB traffic -> ~135 us roofline @ 6.3 TB/s copy ceiling.
// R0 measured 175 us (4.85 TB/s): per-iter biasb load + branch depressed BW.
// R1: scan biasb once -> flag in ws; flag==0 -> pure float4 copy hot loop.

#define NH 25920
#define NS 64
#define ND 64

__device__ __forceinline__ uint32_t rotl32(uint32_t x, int n) {
  return (x << n) | (x >> (32 - n));
}

// JAX threefry2x32 with key = jax.random.key(42) -> (k0,k1) = (0,42).
__device__ __forceinline__ void threefry2x32_0_42(uint32_t x0, uint32_t x1,
                                                  uint32_t& y0, uint32_t& y1) {
  const uint32_t ks0 = 0u;
  const uint32_t ks1 = 42u;
  const uint32_t ks2 = 0u ^ 42u ^ 0x1BD11BDAu;
  x0 += ks0; x1 += ks1;
#define RND(r) { x0 += x1; x1 = rotl32(x1, (r)); x1 ^= x0; }
  RND(13) RND(15) RND(26) RND(6)
  x0 += ks1; x1 += ks2 + 1u;
  RND(17) RND(29) RND(16) RND(24)
  x0 += ks2; x1 += ks0 + 2u;
  RND(13) RND(15) RND(26) RND(6)
  x0 += ks0; x1 += ks1 + 3u;
  RND(17) RND(29) RND(16) RND(24)
  x0 += ks1; x1 += ks2 + 4u;
  RND(13) RND(15) RND(26) RND(6)
  x0 += ks2; x1 += ks0 + 5u;
#undef RND
  y0 = x0; y1 = x1;
}

// Phase 1: one block reduces biasb -> flag (1 if any nonzero). ~104 KB read.
__global__ void __launch_bounds__(1024)
scan_biasb_kernel(const float* __restrict__ biasb, int n,
                  uint32_t* __restrict__ flag) {
  __shared__ int any;
  if (threadIdx.x == 0) any = 0;
  __syncthreads();
  int local = 0;
  for (int i = threadIdx.x; i < n; i += 1024) local |= (biasb[i] != 0.0f);
  if (__any(local) && (threadIdx.x & 63) == 0) atomicOr(&any, 1);
  __syncthreads();
  if (threadIdx.x == 0) *flag = (uint32_t)any;
}

__global__ void __launch_bounds__(256)
fused_residual_kernel(const float4* __restrict__ qt4,
                      const float* __restrict__ biasb,
                      const uint32_t* __restrict__ flag,
                      float4* __restrict__ out4,
                      int total4) {
  const int stride = gridDim.x * 256;
  int i = blockIdx.x * 256 + threadIdx.x;
  if (*flag == 0u) {
    // Hot path: pure streaming copy (biasb == 0 => out = qt).
    int i2 = i + stride;
    for (; i2 < total4; i = i2 + stride, i2 = i + stride) {
      float4 a = qt4[i];
      float4 b = qt4[i2];
      out4[i] = a;
      out4[i2] = b;
    }
    if (i < total4) out4[i] = qt4[i];
    return;
  }
  // Robust fallback: exact JAX bernoulli(key(42), keep, (NH*NS,1)) mask.
  const float keep = 0.2021470392102155f;
  for (; i < total4; i += stride) {
    float4 v = qt4[i];
    const int row = i >> 4;            // h*NS + s ; 16 float4 per row
    const float b = biasb[row >> 6];   // h = row / NS
    float add = 0.0f;
    if (b != 0.0f) {
      const uint32_t n = (uint32_t)(NH * NS);
      const uint32_t half = n >> 1;
      const uint32_t g = (uint32_t)row;
      uint32_t x0, x1, y0, y1;
      const bool hi = (g >= half);
      if (hi) { x0 = g - half; x1 = g; } else { x0 = g; x1 = g + half; }
      threefry2x32_0_42(x0, x1, y0, y1);
      const uint32_t bits = hi ? y1 : y0;
      const float u = __uint_as_float((bits >> 9) | 0x3F800000u) - 1.0f;
      if (u < keep) add = b / keep;    // softmax over singleton == 1
    }
    v.x += add; v.y += add; v.z += add; v.w += add;
    out4[i] = v;
  }
}

extern "C" void kernel_launch(void* const* d_in, const int* in_sizes, int n_in,
                              void* d_out, int out_size, void* d_ws, size_t ws_size,
                              hipStream_t stream) {
  const float4* qt4 = (const float4*)d_in[0];
  // d_in[1] = k (unused), d_in[2] = scaleb (unused)
  const float* biasb = (const float*)d_in[3];
  float4* out4 = (float4*)d_out;
  uint32_t* flag = (uint32_t*)d_ws;

  scan_biasb_kernel<<<1, 1024, 0, stream>>>(biasb, NH, flag);

  const int total4 = (NH * NS * ND) / 4;  // 26,542,080
  fused_residual_kernel<<<4096, 256, 0, stream>>>(qt4, biasb, flag, out4,
                                                  total4);
}

// Round 3
// 163.371 us; speedup vs baseline: 1.2367x; 1.2367x over previous
//
#include <hip/hip_runtime.h>
#include <stdint.h>

// Problem constants (fixed by reference setup_inputs):
//   qt:     (H=25920, S=64, D=64) f32
//   k:      (H, 1, D) f32          -- DEAD: softmax over singleton axis == 1
//   scaleb: (H, 1, 1) f32          -- DEAD: same reason
//   biasb:  (H, 1, 1) f32          -- zeros in setup; a5 = mask * biasb/keep
// out = qt + broadcast(a5) ; a5[h,s] = (bernoulli_keep ? 1/keep : 0) * biasb[h]
//
// Memory-bound: ~850 MB traffic -> ~135 us roofline @ 6.3 TB/s copy ceiling.
// R0: per-element biasb load + branch -> 175 us (4.85 TB/s).
// R1: serial scan kernel + global flag -> 202 us (regression: extra kernel +
//     graph-serialized dependency).
// R2: per-HEAD structure. biasb[h] is wave-uniform (one s_load per 16 KB
//     slab), branch is block-uniform, hot path is a pure coalesced float4
//     copy of the head's contiguous 1024-float4 slab.

#define NH 25920
#define NS 64
#define ND 64
#define HEADS_PER_BLOCK 4

__device__ __forceinline__ uint32_t rotl32(uint32_t x, int n) {
  return (x << n) | (x >> (32 - n));
}

// JAX threefry2x32 with key = jax.random.key(42) -> (k0,k1) = (0,42).
__device__ __forceinline__ void threefry2x32_0_42(uint32_t x0, uint32_t x1,
                                                  uint32_t& y0, uint32_t& y1) {
  const uint32_t ks0 = 0u;
  const uint32_t ks1 = 42u;
  const uint32_t ks2 = 0u ^ 42u ^ 0x1BD11BDAu;
  x0 += ks0; x1 += ks1;
#define RND(r) { x0 += x1; x1 = rotl32(x1, (r)); x1 ^= x0; }
  RND(13) RND(15) RND(26) RND(6)
  x0 += ks1; x1 += ks2 + 1u;
  RND(17) RND(29) RND(16) RND(24)
  x0 += ks2; x1 += ks0 + 2u;
  RND(13) RND(15) RND(26) RND(6)
  x0 += ks0; x1 += ks1 + 3u;
  RND(17) RND(29) RND(16) RND(24)
  x0 += ks1; x1 += ks2 + 4u;
  RND(13) RND(15) RND(26) RND(6)
  x0 += ks2; x1 += ks0 + 5u;
#undef RND
  y0 = x0; y1 = x1;
}

__global__ void __launch_bounds__(256)
fused_residual_kernel(const float4* __restrict__ qt4,
                      const float* __restrict__ biasb,
                      float4* __restrict__ out4) {
  const int h0 = blockIdx.x * HEADS_PER_BLOCK;
#pragma unroll
  for (int hh = 0; hh < HEADS_PER_BLOCK; ++hh) {
    const int h = h0 + hh;
    const float b = biasb[h];   // wave-uniform -> scalar load, 1 per 16 KB
    const int base = h << 10;   // 1024 float4 per head
    if (b == 0.0f) {
      // Hot path: pure streaming copy of this head's slab.
#pragma unroll
      for (int j = 0; j < 4; ++j) {
        const int idx = base + (j << 8) + threadIdx.x;
        out4[idx] = qt4[idx];
      }
    } else {
      // Robust fallback: exact JAX bernoulli(key(42), keep, (NH*NS,1)).
      const float keep = 0.2021470392102155f;
#pragma unroll
      for (int j = 0; j < 4; ++j) {
        const int t = (j << 8) + threadIdx.x;   // 0..1023 within slab
        const int idx = base + t;
        const uint32_t row = (uint32_t)((h << 6) + (t >> 4));  // global row
        const uint32_t n = (uint32_t)(NH * NS);
        const uint32_t half = n >> 1;
        uint32_t x0, x1, y0, y1;
        const bool hi = (row >= half);
        if (hi) { x0 = row - half; x1 = row; } else { x0 = row; x1 = row + half; }
        threefry2x32_0_42(x0, x1, y0, y1);
        const uint32_t bits = hi ? y1 : y0;
        const float u = __uint_as_float((bits >> 9) | 0x3F800000u) - 1.0f;
        const float add = (u < keep) ? (b / keep) : 0.0f;  // softmax(singleton)==1
        float4 v = qt4[idx];
        v.x += add; v.y += add; v.z += add; v.w += add;
        out4[idx] = v;
      }
    }
  }
}

extern "C" void kernel_launch(void* const* d_in, const int* in_sizes, int n_in,
                              void* d_out, int out_size, void* d_ws, size_t ws_size,
                              hipStream_t stream) {
  const float4* qt4 = (const float4*)d_in[0];
  // d_in[1] = k (unused), d_in[2] = scaleb (unused)
  const float* biasb = (const float*)d_in[3];
  float4* out4 = (float4*)d_out;

  const int grid = NH / HEADS_PER_BLOCK;  // 6480 blocks, 4 heads (64 KB) each
  fused_residual_kernel<<<grid, 256, 0, stream>>>(qt4, biasb, out4);
}

// Round 5
// 150.618 us; speedup vs baseline: 1.3414x; 1.0847x over previous
//
#include <hip/hip_runtime.h>
#include <stdint.h>

// Problem constants (fixed by reference setup_inputs):
//   qt:     (H=25920, S=64, D=64) f32
//   k:      (H, 1, D) f32          -- DEAD: softmax over singleton axis == 1
//   scaleb: (H, 1, 1) f32          -- DEAD: same reason
//   biasb:  (H, 1, 1) f32          -- zeros in setup; a5 = mask * biasb/keep
// out = qt + broadcast(a5) ; a5[h,s] = (bernoulli_keep ? 1/keep : 0) * biasb[h]
//
// Memory-bound: ~850 MB traffic -> ~135 us roofline @ 6.3 TB/s copy ceiling.
// R0: per-element biasb load + branch -> 175 us (4.85 TB/s).
// R1: serial scan kernel + global flag -> 202 us (regression).
// R2: per-head slab copy, wave-uniform biasb -> 163 us (5.2 TB/s).
// R3: nontemporal hints -- compile error (builtin rejects HIP_vector_type).
// R4: same experiment with native ext_vector_type float4.

#define NH 25920
#define NS 64
#define ND 64
#define HEADS_PER_BLOCK 4

typedef float f32x4 __attribute__((ext_vector_type(4)));

__device__ __forceinline__ uint32_t rotl32(uint32_t x, int n) {
  return (x << n) | (x >> (32 - n));
}

// JAX threefry2x32 with key = jax.random.key(42) -> (k0,k1) = (0,42).
__device__ __forceinline__ void threefry2x32_0_42(uint32_t x0, uint32_t x1,
                                                  uint32_t& y0, uint32_t& y1) {
  const uint32_t ks0 = 0u;
  const uint32_t ks1 = 42u;
  const uint32_t ks2 = 0u ^ 42u ^ 0x1BD11BDAu;
  x0 += ks0; x1 += ks1;
#define RND(r) { x0 += x1; x1 = rotl32(x1, (r)); x1 ^= x0; }
  RND(13) RND(15) RND(26) RND(6)
  x0 += ks1; x1 += ks2 + 1u;
  RND(17) RND(29) RND(16) RND(24)
  x0 += ks2; x1 += ks0 + 2u;
  RND(13) RND(15) RND(26) RND(6)
  x0 += ks0; x1 += ks1 + 3u;
  RND(17) RND(29) RND(16) RND(24)
  x0 += ks1; x1 += ks2 + 4u;
  RND(13) RND(15) RND(26) RND(6)
  x0 += ks2; x1 += ks0 + 5u;
#undef RND
  y0 = x0; y1 = x1;
}

__global__ void __launch_bounds__(256)
fused_residual_kernel(const f32x4* __restrict__ qt4,
                      const float* __restrict__ biasb,
                      f32x4* __restrict__ out4) {
  const int h0 = blockIdx.x * HEADS_PER_BLOCK;
#pragma unroll
  for (int hh = 0; hh < HEADS_PER_BLOCK; ++hh) {
    const int h = h0 + hh;
    const float b = biasb[h];   // wave-uniform -> scalar load, 1 per 16 KB
    const int base = h << 10;   // 1024 float4 per head
    if (b == 0.0f) {
      // Hot path: pure streaming copy; nt = don't retain in L2/LLC.
#pragma unroll
      for (int j = 0; j < 4; ++j) {
        const int idx = base + (j << 8) + threadIdx.x;
        f32x4 v = __builtin_nontemporal_load(&qt4[idx]);
        __builtin_nontemporal_store(v, &out4[idx]);
      }
    } else {
      // Robust fallback: exact JAX bernoulli(key(42), keep, (NH*NS,1)).
      const float keep = 0.2021470392102155f;
#pragma unroll
      for (int j = 0; j < 4; ++j) {
        const int t = (j << 8) + threadIdx.x;   // 0..1023 within slab
        const int idx = base + t;
        const uint32_t row = (uint32_t)((h << 6) + (t >> 4));  // global row
        const uint32_t n = (uint32_t)(NH * NS);
        const uint32_t half = n >> 1;
        uint32_t x0, x1, y0, y1;
        const bool hi = (row >= half);
        if (hi) { x0 = row - half; x1 = row; } else { x0 = row; x1 = row + half; }
        threefry2x32_0_42(x0, x1, y0, y1);
        const uint32_t bits = hi ? y1 : y0;
        const float u = __uint_as_float((bits >> 9) | 0x3F800000u) - 1.0f;
        const float add = (u < keep) ? (b / keep) : 0.0f;  // softmax(singleton)==1
        f32x4 v = __builtin_nontemporal_load(&qt4[idx]);
        v.x += add; v.y += add; v.z += add; v.w += add;
        __builtin_nontemporal_store(v, &out4[idx]);
      }
    }
  }
}

extern "C" void kernel_launch(void* const* d_in, const int* in_sizes, int n_in,
                              void* d_out, int out_size, void* d_ws, size_t ws_size,
                              hipStream_t stream) {
  const f32x4* qt4 = (const f32x4*)d_in[0];
  // d_in[1] = k (unused), d_in[2] = scaleb (unused)
  const float* biasb = (const float*)d_in[3];
  f32x4* out4 = (f32x4*)d_out;

  const int grid = NH / HEADS_PER_BLOCK;  // 6480 blocks, 4 heads (64 KB) each
  fused_residual_kernel<<<grid, 256, 0, stream>>>(qt4, biasb, out4);
}